// Round 1
// baseline (623.073 us; speedup 1.0000x reference)
//
#include <hip/hip_runtime.h>

// Pixel-adaptive conv: y[c,h,w] = sum_{ii,jj} xp[c,h+ii,w+jj] * k[ii*11+jj,h,w]
// x: (1,3,720,1280) f32, k: (1,121,720,1280) f32, zero padding of 5.
// Memory-bound on the 446 MB k stream -> float4 k loads, 4 pixels/thread.

#define KS   11
#define HALF 5
#define H    720
#define W    1280
#define C    3
#define HW   (H * W)

__global__ __launch_bounds__(256) void apply_pixelwise_conv(
    const float* __restrict__ x,
    const float* __restrict__ k,
    float* __restrict__ out)
{
    const int quadsPerRow = W / 4;            // 320
    const int nQuads      = H * quadsPerRow;  // 230400
    const int tid = blockIdx.x * blockDim.x + threadIdx.x;
    if (tid >= nQuads) return;

    const int h  = tid / quadsPerRow;
    const int w4 = (tid - h * quadsPerRow) * 4;
    const int kbase = h * W + w4;             // multiple of 4 -> 16B aligned

    float acc[C][4];
    #pragma unroll
    for (int c = 0; c < C; ++c)
        #pragma unroll
        for (int p = 0; p < 4; ++p) acc[c][p] = 0.f;

    for (int ii = 0; ii < KS; ++ii) {
        const int  xr       = h + ii - HALF;
        const bool rowValid = (xr >= 0) & (xr < H);
        const int  rowOff   = xr * W;

        // 14-wide x segment per channel covers taps jj=0..10 for 4 pixels.
        float xv[C][KS + 3];
        #pragma unroll
        for (int c = 0; c < C; ++c) {
            #pragma unroll
            for (int j = 0; j < KS + 3; ++j) {
                const int  xc = w4 - HALF + j;
                const bool ok = rowValid & (xc >= 0) & (xc < W);
                xv[c][j] = ok ? x[c * HW + rowOff + xc] : 0.f;
            }
        }

        #pragma unroll
        for (int jj = 0; jj < KS; ++jj) {
            const float4 kv = *reinterpret_cast<const float4*>(
                k + (size_t)(ii * KS + jj) * HW + kbase);
            #pragma unroll
            for (int c = 0; c < C; ++c) {
                acc[c][0] = fmaf(xv[c][jj + 0], kv.x, acc[c][0]);
                acc[c][1] = fmaf(xv[c][jj + 1], kv.y, acc[c][1]);
                acc[c][2] = fmaf(xv[c][jj + 2], kv.z, acc[c][2]);
                acc[c][3] = fmaf(xv[c][jj + 3], kv.w, acc[c][3]);
            }
        }
    }

    #pragma unroll
    for (int c = 0; c < C; ++c) {
        float4 o;
        o.x = acc[c][0]; o.y = acc[c][1]; o.z = acc[c][2]; o.w = acc[c][3];
        *reinterpret_cast<float4*>(out + c * HW + kbase) = o;
    }
}

extern "C" void kernel_launch(void* const* d_in, const int* in_sizes, int n_in,
                              void* d_out, int out_size, void* d_ws, size_t ws_size,
                              hipStream_t stream) {
    const float* x = (const float*)d_in[0];
    const float* k = (const float*)d_in[1];
    // d_in[2] = padding (always 1), d_in[3] = padding_value (always 0) per setup_inputs
    float* out = (float*)d_out;

    const int nQuads = H * (W / 4);           // 230400 threads
    const int block  = 256;
    const int grid   = (nQuads + block - 1) / block;  // 900 blocks
    apply_pixelwise_conv<<<grid, block, 0, stream>>>(x, k, out);
}

// Round 2
// 596.898 us; speedup vs baseline: 1.0439x; 1.0439x over previous
//
#include <hip/hip_runtime.h>

// Pixel-adaptive conv: y[c,h,w] = sum_{ii,jj} xp[c,h+ii,w+jj] * k[ii*11+jj,h,w]
// x: (1,3,720,1280) f32, k: (1,121,720,1280) f32, zero pad 5.
// k stream (446 MB) is the roofline. x staged in LDS per 64x16 tile:
// zero-filled halo (no bounds checks in hot loop), aligned ds_read_b128.

#define KS   11
#define HALF 5
#define H    720
#define W    1280
#define C    3
#define HW   (H * W)

#define TW   64                 // tile width (pixels)
#define TH   16                 // tile height
#define XW   (TW + 2 * HALF + 2)  // 76 floats: halo + pad, keeps rows 16B-aligned
#define XH   (TH + 2 * HALF)      // 26
#define NSTAGE (C * XH * XW)      // 5928 floats

__global__ __launch_bounds__(256) void apply_pixelwise_conv(
    const float* __restrict__ x,
    const float* __restrict__ k,
    float* __restrict__ out)
{
    __shared__ float xs[C][XH][XW];   // 23.7 KB

    const int tx = threadIdx.x & 15;        // quad index in row: w offset tx*4
    const int ty = threadIdx.x >> 4;        // row in tile 0..15
    const int w0 = (blockIdx.x % (W / TW)) * TW;
    const int h0 = (blockIdx.x / (W / TW)) * TH;

    // ---- Stage x tile (+halo) into LDS, zero-filling out-of-bounds ----
    #pragma unroll 1
    for (int idx = threadIdx.x; idx < NSTAGE; idx += 256) {
        const int c   = idx / (XH * XW);
        const int rem = idx - c * (XH * XW);
        const int r   = rem / XW;
        const int col = rem - r * XW;
        const int xr  = h0 - HALF + r;
        const int xc  = w0 - HALF + col;
        float v = 0.f;
        if (col < TW + 2 * HALF && xr >= 0 && xr < H && xc >= 0 && xc < W)
            v = x[c * HW + xr * W + xc];
        xs[c][r][col] = v;
    }
    __syncthreads();

    float acc[C][4];
    #pragma unroll
    for (int c = 0; c < C; ++c)
        #pragma unroll
        for (int p = 0; p < 4; ++p) acc[c][p] = 0.f;

    const int kbase = (h0 + ty) * W + w0 + tx * 4;

    #pragma unroll 1
    for (int ii = 0; ii < KS; ++ii) {
        // xv[c][j] = xs[c][ty+ii][tx*4 + j], j=0..13 — aligned vector LDS reads
        float xv[C][KS + 3];
        #pragma unroll
        for (int c = 0; c < C; ++c) {
            const float* rowp = &xs[c][ty + ii][tx * 4];
            const float4 a = *reinterpret_cast<const float4*>(rowp);
            const float4 b = *reinterpret_cast<const float4*>(rowp + 4);
            const float4 d = *reinterpret_cast<const float4*>(rowp + 8);
            const float2 e = *reinterpret_cast<const float2*>(rowp + 12);
            xv[c][0] = a.x;  xv[c][1] = a.y;  xv[c][2]  = a.z;  xv[c][3]  = a.w;
            xv[c][4] = b.x;  xv[c][5] = b.y;  xv[c][6]  = b.z;  xv[c][7]  = b.w;
            xv[c][8] = d.x;  xv[c][9] = d.y;  xv[c][10] = d.z;  xv[c][11] = d.w;
            xv[c][12] = e.x; xv[c][13] = e.y;
        }

        #pragma unroll
        for (int jj = 0; jj < KS; ++jj) {
            const float4 kv = *reinterpret_cast<const float4*>(
                k + (size_t)(ii * KS + jj) * HW + kbase);
            #pragma unroll
            for (int c = 0; c < C; ++c) {
                acc[c][0] = fmaf(xv[c][jj + 0], kv.x, acc[c][0]);
                acc[c][1] = fmaf(xv[c][jj + 1], kv.y, acc[c][1]);
                acc[c][2] = fmaf(xv[c][jj + 2], kv.z, acc[c][2]);
                acc[c][3] = fmaf(xv[c][jj + 3], kv.w, acc[c][3]);
            }
        }
    }

    #pragma unroll
    for (int c = 0; c < C; ++c) {
        float4 o;
        o.x = acc[c][0]; o.y = acc[c][1]; o.z = acc[c][2]; o.w = acc[c][3];
        *reinterpret_cast<float4*>(out + c * HW + kbase) = o;
    }
}

extern "C" void kernel_launch(void* const* d_in, const int* in_sizes, int n_in,
                              void* d_out, int out_size, void* d_ws, size_t ws_size,
                              hipStream_t stream) {
    const float* x = (const float*)d_in[0];
    const float* k = (const float*)d_in[1];
    float* out = (float*)d_out;

    const int grid = (W / TW) * (H / TH);   // 20 * 45 = 900 blocks
    apply_pixelwise_conv<<<grid, 256, 0, stream>>>(x, k, out);
}